// Round 2
// baseline (1091.522 us; speedup 1.0000x reference)
//
#include <hip/hip_runtime.h>
#include <math.h>

#define Bn 4
#define Cn 256
#define CKn 64
#define Nn 4096
#define EPSf 1e-5f

// ---- workspace layout (float offsets), total = 6,357,120 floats (~25.4 MB) ----
#define OFF_WEFFB 0                       // CKn*Cn
#define OFF_WEFFC 16384                   // CKn*Cn
#define OFF_BEFFB 32768                   // 64
#define OFF_BEFFC 32832                   // 64
#define OFF_ROWM  32896                   // Bn*Nn
#define OFF_ROWZ  49280                   // Bn*Nn
#define OFF_FA    65664                   // Bn*CKn*Nn
#define OFF_FB    (65664 + 1048576)       // Bn*CKn*Nn
#define OFF_F1T   (65664 + 2*1048576)     // Bn*Nn*Cn   (transposed: [n][c])

// ---------------------------------------------------------------------------
// Fold BN (eval mode) into the 1x1 conv weights.
// grid (CKn, 2), block 256.  y=0 -> (Wb,bb)->Weffb, y=1 -> (Wc,bc)->Weffc
// ---------------------------------------------------------------------------
__global__ __launch_bounds__(256)
void k_fold(const float* __restrict__ Wb, const float* __restrict__ bb,
            const float* __restrict__ Wc, const float* __restrict__ bc,
            const float* __restrict__ gamma, const float* __restrict__ beta,
            const float* __restrict__ mean, const float* __restrict__ var,
            float* __restrict__ ws) {
  const int k = blockIdx.x;
  const int which = blockIdx.y;
  const int c = threadIdx.x;
  const float* W = which ? Wc : Wb;
  const float* bias = which ? bc : bb;
  float* Weff = ws + (which ? OFF_WEFFC : OFF_WEFFB);
  float* beff = ws + (which ? OFF_BEFFC : OFF_BEFFB);
  float s = gamma[c] * rsqrtf(var[c] + EPSf);
  float tt = beta[c] - mean[c] * s;
  float w = W[k * Cn + c];
  Weff[k * Cn + c] = w * s;
  __shared__ float red[256];
  red[c] = w * tt;
  __syncthreads();
  for (int off = 128; off > 0; off >>= 1) {
    if (c < off) red[c] += red[c + off];
    __syncthreads();
  }
  if (c == 0) beff[k] = bias[k] + red[0];
}

// ---------------------------------------------------------------------------
// fa = Weffb @ x1 + beffb ; fb = Weffc @ x2 + beffc   (layout [b][k][n])
// grid (Nn/128, 2, Bn), block 256. Tile 64oc x 128n, micro 4oc x 8n.
// ---------------------------------------------------------------------------
__global__ __launch_bounds__(256)
void k_feat_ab(const float* __restrict__ x1, const float* __restrict__ x2,
               float* __restrict__ ws) {
  const int n0 = blockIdx.x * 128;
  const int which = blockIdx.y;
  const int b = blockIdx.z;
  const float* W = ws + (which ? OFF_WEFFC : OFF_WEFFB);
  const float* bias = ws + (which ? OFF_BEFFC : OFF_BEFFB);
  const float* X = (which ? x2 : x1) + b * Cn * Nn;
  float* Y = ws + (which ? OFF_FB : OFF_FA) + b * CKn * Nn;

  __shared__ __align__(16) float Wsh[16][68];   // [kk][oc]
  __shared__ __align__(16) float Xsh[16][132];  // [kk][n]
  const int t = threadIdx.x;
  const int to = t >> 4;   // 0..15 : oc = to*4 + jo
  const int tn = t & 15;   // n = tn*8 + jn

  float acc[4][8];
#pragma unroll
  for (int i = 0; i < 4; i++)
#pragma unroll
    for (int j = 0; j < 8; j++) acc[i][j] = 0.f;

  for (int k0 = 0; k0 < Cn; k0 += 16) {
    __syncthreads();
#pragma unroll
    for (int i = 0; i < 4; i++) {
      int e = t + 256 * i;
      Wsh[e & 15][e >> 4] = W[(e >> 4) * Cn + k0 + (e & 15)];
    }
#pragma unroll
    for (int i = 0; i < 2; i++) {
      int e4 = t + 256 * i;            // [0,512): kk = e4>>5, n4 = e4&31
      *(float4*)&Xsh[e4 >> 5][(e4 & 31) * 4] =
          *(const float4*)&X[(k0 + (e4 >> 5)) * Nn + n0 + (e4 & 31) * 4];
    }
    __syncthreads();
#pragma unroll
    for (int kk = 0; kk < 16; kk++) {
      float4 a4 = *(const float4*)&Wsh[kk][to * 4];
      float4 x0 = *(const float4*)&Xsh[kk][tn * 8];
      float4 x1v = *(const float4*)&Xsh[kk][tn * 8 + 4];
      float av[4] = {a4.x, a4.y, a4.z, a4.w};
      float xv[8] = {x0.x, x0.y, x0.z, x0.w, x1v.x, x1v.y, x1v.z, x1v.w};
#pragma unroll
      for (int i = 0; i < 4; i++)
#pragma unroll
        for (int j = 0; j < 8; j++) acc[i][j] = fmaf(av[i], xv[j], acc[i][j]);
    }
  }
#pragma unroll
  for (int jo = 0; jo < 4; jo++) {
    int oc = to * 4 + jo;
    float bv = bias[oc];
    float4 o0 = make_float4(acc[jo][0] + bv, acc[jo][1] + bv, acc[jo][2] + bv, acc[jo][3] + bv);
    float4 o1 = make_float4(acc[jo][4] + bv, acc[jo][5] + bv, acc[jo][6] + bv, acc[jo][7] + bv);
    *(float4*)&Y[oc * Nn + n0 + tn * 8] = o0;
    *(float4*)&Y[oc * Nn + n0 + tn * 8 + 4] = o1;
  }
}

// ---------------------------------------------------------------------------
// f1T[b][n][c] = (Wd @ x + bd)^T  (transposed so the PV GEMM reads coalesced)
// grid (Nn/128, Cn/64, Bn), block 256. Tile 128n x 64c, micro 8n x 4c.
// ---------------------------------------------------------------------------
__global__ __launch_bounds__(256)
void k_feat_d(const float* __restrict__ x, const float* __restrict__ Wd,
              const float* __restrict__ bd, float* __restrict__ ws) {
  const int n0 = blockIdx.x * 128;
  const int c0 = blockIdx.y * 64;
  const int b = blockIdx.z;
  const float* X = x + b * Cn * Nn;
  float* f1T = ws + OFF_F1T + b * Cn * Nn;

  __shared__ __align__(16) float Wsh[16][68];   // [kk][c]
  __shared__ __align__(16) float Xsh[16][132];  // [kk][n]
  const int t = threadIdx.x;
  const int tn = t >> 4;  // n = tn*8 + jn
  const int tc = t & 15;  // c = tc*4 + jc

  float acc[8][4];
#pragma unroll
  for (int i = 0; i < 8; i++)
#pragma unroll
    for (int j = 0; j < 4; j++) acc[i][j] = 0.f;

  for (int k0 = 0; k0 < Cn; k0 += 16) {
    __syncthreads();
#pragma unroll
    for (int i = 0; i < 4; i++) {
      int e = t + 256 * i;
      Wsh[e & 15][e >> 4] = Wd[(c0 + (e >> 4)) * Cn + k0 + (e & 15)];
    }
#pragma unroll
    for (int i = 0; i < 2; i++) {
      int e4 = t + 256 * i;
      *(float4*)&Xsh[e4 >> 5][(e4 & 31) * 4] =
          *(const float4*)&X[(k0 + (e4 >> 5)) * Nn + n0 + (e4 & 31) * 4];
    }
    __syncthreads();
#pragma unroll
    for (int kk = 0; kk < 16; kk++) {
      float4 w4 = *(const float4*)&Wsh[kk][tc * 4];
      float4 x0 = *(const float4*)&Xsh[kk][tn * 8];
      float4 x1v = *(const float4*)&Xsh[kk][tn * 8 + 4];
      float wv[4] = {w4.x, w4.y, w4.z, w4.w};
      float xv[8] = {x0.x, x0.y, x0.z, x0.w, x1v.x, x1v.y, x1v.z, x1v.w};
#pragma unroll
      for (int i = 0; i < 8; i++)
#pragma unroll
        for (int j = 0; j < 4; j++) acc[i][j] = fmaf(xv[i], wv[j], acc[i][j]);
    }
  }
  float4 b4 = *(const float4*)&bd[c0 + tc * 4];
#pragma unroll
  for (int jn = 0; jn < 8; jn++) {
    int n = n0 + tn * 8 + jn;
    float4 o = make_float4(acc[jn][0] + b4.x, acc[jn][1] + b4.y,
                           acc[jn][2] + b4.z, acc[jn][3] + b4.w);
    *(float4*)&f1T[n * Cn + c0 + tc * 4] = o;
  }
}

// ---------------------------------------------------------------------------
// Per-row softmax stats: rowM = max_j s[r,j], rowZinv = 1/sum_j exp(s-M).
// grid (Nn/64, Bn), block 512 (8 waves/CU). Tile 64m x 256n, micro 4m x 8n
// (n split as two float4 chunks at tn*4 and tn*4+128 -> 4-way streaming LDS).
// ---------------------------------------------------------------------------
__global__ __launch_bounds__(512)
void k_stats(float* __restrict__ ws) {
  const int m0 = blockIdx.x * 64;
  const int b = blockIdx.y;
  const float* fa = ws + OFF_FA + b * CKn * Nn;
  const float* fb = ws + OFF_FB + b * CKn * Nn;

  __shared__ __align__(16) float fas[64][68];    // [k][m]
  __shared__ __align__(16) float fbs[64][260];   // [k][n]
  const int t = threadIdx.x;
  const int tm = t >> 5;  // 0..15 : m = tm*4 + jm
  const int tn = t & 31;  // n = tn*4+q  and  128 + tn*4+q

#pragma unroll
  for (int i = 0; i < 2; i++) {
    int e4 = t + 512 * i;              // [0,1024): k = e4>>4, m4 = e4&15
    *(float4*)&fas[e4 >> 4][(e4 & 15) * 4] =
        *(const float4*)&fa[(e4 >> 4) * Nn + m0 + (e4 & 15) * 4];
  }

  float M[4], Z[4];
#pragma unroll
  for (int j = 0; j < 4; j++) { M[j] = -1e30f; Z[j] = 0.f; }

  for (int nt = 0; nt < 16; nt++) {
    const int nb = nt * 256;
    __syncthreads();
#pragma unroll
    for (int i = 0; i < 8; i++) {
      int e4 = t + 512 * i;            // [0,4096): k = e4>>6, n4 = e4&63
      *(float4*)&fbs[e4 >> 6][(e4 & 63) * 4] =
          *(const float4*)&fb[(e4 >> 6) * Nn + nb + (e4 & 63) * 4];
    }
    __syncthreads();
    float s[4][8];
#pragma unroll
    for (int i = 0; i < 4; i++)
#pragma unroll
      for (int j = 0; j < 8; j++) s[i][j] = 0.f;
#pragma unroll 4
    for (int k = 0; k < 64; k++) {
      float4 a0 = *(const float4*)&fas[k][tm * 4];
      float4 b0 = *(const float4*)&fbs[k][tn * 4];
      float4 b1 = *(const float4*)&fbs[k][tn * 4 + 128];
      float av[4] = {a0.x, a0.y, a0.z, a0.w};
      float bv[8] = {b0.x, b0.y, b0.z, b0.w, b1.x, b1.y, b1.z, b1.w};
#pragma unroll
      for (int i = 0; i < 4; i++)
#pragma unroll
        for (int j = 0; j < 8; j++) s[i][j] = fmaf(av[i], bv[j], s[i][j]);
    }
#pragma unroll
    for (int jm = 0; jm < 4; jm++) {
      float t0 = fmaxf(fmaxf(s[jm][0], s[jm][1]), fmaxf(s[jm][2], s[jm][3]));
      float t1 = fmaxf(fmaxf(s[jm][4], s[jm][5]), fmaxf(s[jm][6], s[jm][7]));
      float nm = fmaxf(M[jm], fmaxf(t0, t1));
      float zs = Z[jm] * __expf(M[jm] - nm);
#pragma unroll
      for (int jn = 0; jn < 8; jn++) zs += __expf(s[jm][jn] - nm);
      Z[jm] = zs; M[jm] = nm;
    }
  }
  // reduce (M,Z) across the 32 tn-lanes (same-tm lanes are a contiguous 32-half)
  for (int off = 1; off < 32; off <<= 1) {
#pragma unroll
    for (int jm = 0; jm < 4; jm++) {
      float oM = __shfl_xor(M[jm], off, 64);
      float oZ = __shfl_xor(Z[jm], off, 64);
      float nm = fmaxf(M[jm], oM);
      Z[jm] = Z[jm] * __expf(M[jm] - nm) + oZ * __expf(oM - nm);
      M[jm] = nm;
    }
  }
  if (tn == 0) {
#pragma unroll
    for (int jm = 0; jm < 4; jm++) {
      int m = m0 + tm * 4 + jm;
      ws[OFF_ROWM + b * Nn + m] = M[jm];
      ws[OFF_ROWZ + b * Nn + m] = 1.0f / Z[jm];
    }
  }
}

// ---------------------------------------------------------------------------
// Fused: recompute score tile -> att tile (LDS) -> PV GEMM -> out = a*feat + x
// grid (Nn/64, Bn), block 512.
// Phase A: 64m x 128n scores, micro 4m x 4n. Phase B: out 256c x 64m,
// micro 8c x 4m, f1T rows read straight from global (L2-resident).
// ---------------------------------------------------------------------------
__global__ __launch_bounds__(512)
void k_attn_out(const float* __restrict__ x, const float* __restrict__ alphaPtr,
                const float* __restrict__ wsc, float* __restrict__ out) {
  const int m0 = blockIdx.x * 64;
  const int b = blockIdx.y;
  const float* fa = wsc + OFF_FA + b * CKn * Nn;
  const float* fb = wsc + OFF_FB + b * CKn * Nn;
  const float* f1T = wsc + OFF_F1T + b * Cn * Nn;
  const float* rowM = wsc + OFF_ROWM + b * Nn;
  const float* rowZ = wsc + OFF_ROWZ + b * Nn;

  __shared__ __align__(16) float fas[64][64];    // [k][m]
  __shared__ __align__(16) float fbs[64][128];   // [k][n]
  __shared__ __align__(16) float attT[128][68];  // [n][m]

  const int t = threadIdx.x;
#pragma unroll
  for (int i = 0; i < 2; i++) {
    int e4 = t + 512 * i;              // [0,1024): k = e4>>4, m4 = e4&15
    *(float4*)&fas[e4 >> 4][(e4 & 15) * 4] =
        *(const float4*)&fa[(e4 >> 4) * Nn + m0 + (e4 & 15) * 4];
  }
  const int tmA = t >> 5;  // 0..15 : m = tmA*4 + jm
  const int tnA = t & 31;  // n = tnA*4 + jn
  float Mv[4], Zi[4];
#pragma unroll
  for (int jm = 0; jm < 4; jm++) {
    Mv[jm] = rowM[m0 + tmA * 4 + jm];
    Zi[jm] = rowZ[m0 + tmA * 4 + jm];
  }
  const int tcB = t >> 4;  // 0..31 : c = tcB*8 + jc
  const int tmB = t & 15;  // m = tmB*4 + jm
  float acc[8][4];
#pragma unroll
  for (int i = 0; i < 8; i++)
#pragma unroll
    for (int j = 0; j < 4; j++) acc[i][j] = 0.f;

  for (int nt = 0; nt < 32; nt++) {
    const int nb = nt * 128;
    __syncthreads();  // protects fbs (phase-A readers) & attT (phase-B readers)
#pragma unroll
    for (int i = 0; i < 4; i++) {
      int e4 = t + 512 * i;            // [0,2048): k = e4>>5, n4 = e4&31
      *(float4*)&fbs[e4 >> 5][(e4 & 31) * 4] =
          *(const float4*)&fb[(e4 >> 5) * Nn + nb + (e4 & 31) * 4];
    }
    __syncthreads();
    // --- phase A: scores + att ---
    float s[4][4];
#pragma unroll
    for (int i = 0; i < 4; i++)
#pragma unroll
      for (int j = 0; j < 4; j++) s[i][j] = 0.f;
#pragma unroll 4
    for (int k = 0; k < 64; k++) {
      float4 a4 = *(const float4*)&fas[k][tmA * 4];
      float4 b4 = *(const float4*)&fbs[k][tnA * 4];
      float av[4] = {a4.x, a4.y, a4.z, a4.w};
      float bv[4] = {b4.x, b4.y, b4.z, b4.w};
#pragma unroll
      for (int i = 0; i < 4; i++)
#pragma unroll
        for (int j = 0; j < 4; j++) s[i][j] = fmaf(av[i], bv[j], s[i][j]);
    }
#pragma unroll
    for (int jn = 0; jn < 4; jn++) {
      float w[4];
#pragma unroll
      for (int jm = 0; jm < 4; jm++) {
        float p = __expf(s[jm][jn] - Mv[jm]) * Zi[jm];   // softmax prob
        w[jm] = 1.0f / (1.0f + __expf(p));               // 1 - sigmoid(p)
      }
      *(float4*)&attT[tnA * 4 + jn][tmA * 4] = make_float4(w[0], w[1], w[2], w[3]);
    }
    __syncthreads();
    // --- phase B: acc[c][m] += f1T[n][c] * attT[n][m] ---
    const float* f1p = f1T + nb * Cn + tcB * 8;
#pragma unroll 2
    for (int ni = 0; ni < 128; ni++) {
      float4 a4 = *(const float4*)&attT[ni][tmB * 4];
      float4 c0 = *(const float4*)(f1p + ni * Cn);
      float4 c1 = *(const float4*)(f1p + ni * Cn + 4);
      float av[4] = {a4.x, a4.y, a4.z, a4.w};
      float cf[8] = {c0.x, c0.y, c0.z, c0.w, c1.x, c1.y, c1.z, c1.w};
#pragma unroll
      for (int jc = 0; jc < 8; jc++)
#pragma unroll
        for (int jm = 0; jm < 4; jm++) acc[jc][jm] = fmaf(cf[jc], av[jm], acc[jc][jm]);
    }
  }
  const float alpha = alphaPtr[0];
#pragma unroll
  for (int jc = 0; jc < 8; jc++) {
    int c = tcB * 8 + jc;
    int base = (b * Cn + c) * Nn + m0 + tmB * 4;
    float4 xv = *(const float4*)&x[base];
    float4 o = make_float4(fmaf(alpha, acc[jc][0], xv.x), fmaf(alpha, acc[jc][1], xv.y),
                           fmaf(alpha, acc[jc][2], xv.z), fmaf(alpha, acc[jc][3], xv.w));
    *(float4*)&out[base] = o;
  }
}

// ---------------------------------------------------------------------------
extern "C" void kernel_launch(void* const* d_in, const int* in_sizes, int n_in,
                              void* d_out, int out_size, void* d_ws, size_t ws_size,
                              hipStream_t stream) {
  (void)in_sizes; (void)n_in; (void)out_size; (void)ws_size;
  const float* x1    = (const float*)d_in[0];
  const float* x2    = (const float*)d_in[1];
  const float* x     = (const float*)d_in[2];
  const float* gamma = (const float*)d_in[3];
  const float* beta  = (const float*)d_in[4];
  const float* mean  = (const float*)d_in[5];
  const float* var   = (const float*)d_in[6];
  const float* Wb    = (const float*)d_in[7];
  const float* bb    = (const float*)d_in[8];
  const float* Wc    = (const float*)d_in[9];
  const float* bc    = (const float*)d_in[10];
  const float* Wd    = (const float*)d_in[11];
  const float* bd    = (const float*)d_in[12];
  const float* alpha = (const float*)d_in[13];
  float* out = (float*)d_out;
  float* ws  = (float*)d_ws;

  k_fold<<<dim3(CKn, 2), 256, 0, stream>>>(Wb, bb, Wc, bc, gamma, beta, mean, var, ws);
  k_feat_ab<<<dim3(Nn / 128, 2, Bn), 256, 0, stream>>>(x1, x2, ws);
  k_feat_d<<<dim3(Nn / 128, Cn / 64, Bn), 256, 0, stream>>>(x, Wd, bd, ws);
  k_stats<<<dim3(Nn / 64, Bn), 512, 0, stream>>>(ws);
  k_attn_out<<<dim3(Nn / 64, Bn), 512, 0, stream>>>(x, alpha, ws, out);
}

// Round 4
// 314.725 us; speedup vs baseline: 3.4682x; 3.4682x over previous
//
#include <hip/hip_runtime.h>
#include <math.h>

#define Bn 4
#define Cn 256
#define CKn 64
#define Nn 4096
#define EPSf 1e-5f

// ---- fp32 ws region (float offsets) ----
#define OFF_WEFFB 0        // 16384
#define OFF_WEFFC 16384    // 16384
#define OFF_BEFFB 32768    // 64
#define OFF_BEFFC 32832    // 64
#define OFF_S1    32896    // Bn*Cn = 1024 (fp32 column sums of f1, atomic)
#define OFF_BF16  33920    // bf16 region starts here (byte off 135680, 16B aligned)
// ---- bf16 region (u16 offsets from OFF_BF16) ----
// FA  [b][n][64]  : b*262144 + n*64 + k        (1,048,576)
// FB  [b][n][64]  : 1048576 + same             (1,048,576)
// F1  [b][c][n]   : 2097152 + b*1048576 + c*4096 + n   (4,194,304)

typedef unsigned short u16;
using bf16x8 = __attribute__((ext_vector_type(8))) __bf16;
using f32x4  = __attribute__((ext_vector_type(4))) float;

__device__ __forceinline__ u16 f2b(float x) {
  __bf16 h = (__bf16)x;
  return __builtin_bit_cast(unsigned short, h);
}

// ---------------------------------------------------------------------------
// Fold BN into 1x1 conv weights; also zero S1. grid (64,2), block 256.
// ---------------------------------------------------------------------------
__global__ __launch_bounds__(256)
void k_fold(const float* __restrict__ Wb, const float* __restrict__ bb,
            const float* __restrict__ Wc, const float* __restrict__ bc,
            const float* __restrict__ gamma, const float* __restrict__ beta,
            const float* __restrict__ mean, const float* __restrict__ var,
            float* __restrict__ ws) {
  const int k = blockIdx.x;
  const int which = blockIdx.y;
  const int c = threadIdx.x;
  if (which == 0 && k < Bn) ws[OFF_S1 + k * Cn + c] = 0.f;   // zero S1 (poisoned ws)
  const float* W = which ? Wc : Wb;
  const float* bias = which ? bc : bb;
  float* Weff = ws + (which ? OFF_WEFFC : OFF_WEFFB);
  float* beff = ws + (which ? OFF_BEFFC : OFF_BEFFB);
  float s = gamma[c] * rsqrtf(var[c] + EPSf);
  float tt = beta[c] - mean[c] * s;
  float w = W[k * Cn + c];
  Weff[k * Cn + c] = w * s;
  __shared__ float red[256];
  red[c] = w * tt;
  __syncthreads();
  for (int off = 128; off > 0; off >>= 1) {
    if (c < off) red[c] += red[c + off];
    __syncthreads();
  }
  if (c == 0) beff[k] = bias[k] + red[0];
}

// ---------------------------------------------------------------------------
// fa/fb = BN-folded 1x1 conv, written bf16 [b][n][64] (n-major, K contiguous).
// grid (Nn/128, 2, Bn), block 256. fp32 compute (tile 64oc x 128n).
// ---------------------------------------------------------------------------
__global__ __launch_bounds__(256)
void k_feat_ab(const float* __restrict__ x1, const float* __restrict__ x2,
               float* __restrict__ ws) {
  const int n0 = blockIdx.x * 128;
  const int which = blockIdx.y;
  const int b = blockIdx.z;
  const float* W = ws + (which ? OFF_WEFFC : OFF_WEFFB);
  const float* bias = ws + (which ? OFF_BEFFC : OFF_BEFFB);
  const float* X = (which ? x2 : x1) + b * Cn * Nn;
  u16* Y = (u16*)(ws + OFF_BF16) + (which ? 1048576 : 0) + b * 262144;

  __shared__ __align__(16) float Wsh[16][68];   // [kk][oc]
  __shared__ __align__(16) float Xsh[16][132];  // [kk][n]
  const int t = threadIdx.x;
  const int to = t >> 4;   // oc = to*4 + jo
  const int tn = t & 15;   // n  = tn*8 + jn

  float acc[4][8];
#pragma unroll
  for (int i = 0; i < 4; i++)
#pragma unroll
    for (int j = 0; j < 8; j++) acc[i][j] = 0.f;

  for (int k0 = 0; k0 < Cn; k0 += 16) {
    __syncthreads();
#pragma unroll
    for (int i = 0; i < 4; i++) {
      int e = t + 256 * i;
      Wsh[e & 15][e >> 4] = W[(e >> 4) * Cn + k0 + (e & 15)];
    }
#pragma unroll
    for (int i = 0; i < 2; i++) {
      int e4 = t + 256 * i;
      *(float4*)&Xsh[e4 >> 5][(e4 & 31) * 4] =
          *(const float4*)&X[(k0 + (e4 >> 5)) * Nn + n0 + (e4 & 31) * 4];
    }
    __syncthreads();
#pragma unroll
    for (int kk = 0; kk < 16; kk++) {
      float4 a4 = *(const float4*)&Wsh[kk][to * 4];
      float4 x0 = *(const float4*)&Xsh[kk][tn * 8];
      float4 x1v = *(const float4*)&Xsh[kk][tn * 8 + 4];
      float av[4] = {a4.x, a4.y, a4.z, a4.w};
      float xv[8] = {x0.x, x0.y, x0.z, x0.w, x1v.x, x1v.y, x1v.z, x1v.w};
#pragma unroll
      for (int i = 0; i < 4; i++)
#pragma unroll
        for (int j = 0; j < 8; j++) acc[i][j] = fmaf(av[i], xv[j], acc[i][j]);
    }
  }
  float bv[4];
#pragma unroll
  for (int jo = 0; jo < 4; jo++) bv[jo] = bias[to * 4 + jo];
#pragma unroll
  for (int jn = 0; jn < 8; jn++) {
    int n = n0 + tn * 8 + jn;
    union { u16 h[4]; uint2 v; } pk;
#pragma unroll
    for (int jo = 0; jo < 4; jo++) pk.h[jo] = f2b(acc[jo][jn] + bv[jo]);
    *(uint2*)&Y[n * 64 + to * 4] = pk.v;
  }
}

// ---------------------------------------------------------------------------
// f1 = Wd @ x + bd, written bf16 [b][c][n]; S1[b][c] += fp32 row-partials.
// grid (Nn/128, Cn/64, Bn), block 256. fp32 compute.
// ---------------------------------------------------------------------------
__global__ __launch_bounds__(256)
void k_feat_d(const float* __restrict__ x, const float* __restrict__ Wd,
              const float* __restrict__ bd, float* __restrict__ ws) {
  const int n0 = blockIdx.x * 128;
  const int c0 = blockIdx.y * 64;
  const int b = blockIdx.z;
  const float* X = x + b * Cn * Nn;
  u16* F1 = (u16*)(ws + OFF_BF16) + 2097152 + b * 1048576;
  float* S1 = ws + OFF_S1 + b * Cn;

  __shared__ __align__(16) float Wsh[16][68];   // [kk][c]
  __shared__ __align__(16) float Xsh[16][132];  // [kk][n]
  const int t = threadIdx.x;
  const int tn = t >> 4;  // n = tn*8 + jn
  const int tc = t & 15;  // c = tc*4 + jc

  float acc[8][4];
#pragma unroll
  for (int i = 0; i < 8; i++)
#pragma unroll
    for (int j = 0; j < 4; j++) acc[i][j] = 0.f;

  for (int k0 = 0; k0 < Cn; k0 += 16) {
    __syncthreads();
#pragma unroll
    for (int i = 0; i < 4; i++) {
      int e = t + 256 * i;
      Wsh[e & 15][e >> 4] = Wd[(c0 + (e >> 4)) * Cn + k0 + (e & 15)];
    }
#pragma unroll
    for (int i = 0; i < 2; i++) {
      int e4 = t + 256 * i;
      *(float4*)&Xsh[e4 >> 5][(e4 & 31) * 4] =
          *(const float4*)&X[(k0 + (e4 >> 5)) * Nn + n0 + (e4 & 31) * 4];
    }
    __syncthreads();
#pragma unroll
    for (int kk = 0; kk < 16; kk++) {
      float4 w4 = *(const float4*)&Wsh[kk][tc * 4];
      float4 x0 = *(const float4*)&Xsh[kk][tn * 8];
      float4 x1v = *(const float4*)&Xsh[kk][tn * 8 + 4];
      float wv[4] = {w4.x, w4.y, w4.z, w4.w};
      float xv[8] = {x0.x, x0.y, x0.z, x0.w, x1v.x, x1v.y, x1v.z, x1v.w};
#pragma unroll
      for (int i = 0; i < 8; i++)
#pragma unroll
        for (int j = 0; j < 4; j++) acc[i][j] = fmaf(xv[i], wv[j], acc[i][j]);
    }
  }
  float4 b4 = *(const float4*)&bd[c0 + tc * 4];
  float bvj[4] = {b4.x, b4.y, b4.z, b4.w};
  float psum[4];
#pragma unroll
  for (int jc = 0; jc < 4; jc++) {
    union { u16 h[8]; uint4 v; } pk;
    float ps = 0.f;
#pragma unroll
    for (int jn = 0; jn < 8; jn++) {
      float vv = acc[jn][jc] + bvj[jc];
      pk.h[jn] = f2b(vv);
      ps += vv;                              // fp32 pre-rounding sum (common mode)
    }
    *(uint4*)&F1[(c0 + tc * 4 + jc) * Nn + n0 + tn * 8] = pk.v;
    psum[jc] = ps;
  }
  // reduce psum across the 4 tn-subgroups within this wave, then atomicAdd.
#pragma unroll
  for (int off = 16; off <= 32; off <<= 1)
#pragma unroll
    for (int jc = 0; jc < 4; jc++) psum[jc] += __shfl_xor(psum[jc], off, 64);
  if ((t & 63) < 16) {
#pragma unroll
    for (int jc = 0; jc < 4; jc++)
      atomicAdd(&S1[c0 + (t & 15) * 4 + jc], psum[jc]);
  }
}

// ---------------------------------------------------------------------------
// Fused stats + attention + PV, all MFMA bf16.
// grid (Nn/64, Bn), block 512 (8 waves).
// Wave w: phase A owns n-stripe w*16 (of each 128-tile), all 4 m-tiles;
//         phase B owns c-range w*32 (2 c-tiles), all 4 m-tiles.
// d = att - 0.5 = -0.5*tanh(p/2), p = exp(s - M) / Z  (x = p/2 via Zi2 = 0.5/Z)
// out[c,m] = alpha*(0.5*S1[c] + sum_n f1[c,n]*d[m,n]) + x[c,m]
// ---------------------------------------------------------------------------
__global__ __launch_bounds__(512)
void k_fused(const float* __restrict__ x, const float* __restrict__ alphaPtr,
             const float* __restrict__ wsf, float* __restrict__ out) {
  const int m0 = blockIdx.x * 64;
  const int b = blockIdx.y;
  const u16* bf = (const u16*)(wsf + OFF_BF16);
  const u16* FA = bf + b * 262144;
  const u16* FB = bf + 1048576 + b * 262144;
  const u16* F1 = bf + 2097152 + b * 1048576;
  const float* S1 = wsf + OFF_S1 + b * Cn;

  const int t = threadIdx.x;
  const int wave = t >> 6, lane = t & 63, lo = lane & 15, hi = lane >> 4;

  __shared__ u16 d_lds[64 * 128];            // swizzled [m][n ^ ((m&7)*8)]
  __shared__ float redM[8][64], redZ[8][64];
  __shared__ float statM[64], statZ[64];     // M*, 0.5/Z*

  // hoisted fa fragments (B-operand of score MFMA): B[k][col=m]
  bf16x8 faf[4][2];
#pragma unroll
  for (int mt = 0; mt < 4; mt++)
#pragma unroll
    for (int ks = 0; ks < 2; ks++)
      faf[mt][ks] = *(const bf16x8*)&FA[(m0 + mt * 16 + lo) * 64 + ks * 32 + hi * 8];

  // ---- stats pass: rowM / rowZ over all n (no barriers) ----
  float Mx[4], Zs[4];
#pragma unroll
  for (int mt = 0; mt < 4; mt++) { Mx[mt] = -1e30f; Zs[mt] = 0.f; }

  for (int it = 0; it < 32; it++) {
    const int nr = it * 128 + wave * 16 + lo;   // A-operand row = n
    bf16x8 fb0 = *(const bf16x8*)&FB[nr * 64 + hi * 8];
    bf16x8 fb1 = *(const bf16x8*)&FB[nr * 64 + 32 + hi * 8];
    f32x4 sc[4];
#pragma unroll
    for (int mt = 0; mt < 4; mt++) {
      f32x4 z = {0.f, 0.f, 0.f, 0.f};
      z = __builtin_amdgcn_mfma_f32_16x16x32_bf16(fb0, faf[mt][0], z, 0, 0, 0);
      sc[mt] = __builtin_amdgcn_mfma_f32_16x16x32_bf16(fb1, faf[mt][1], z, 0, 0, 0);
    }
#pragma unroll
    for (int mt = 0; mt < 4; mt++) {
      float s0 = sc[mt][0], s1 = sc[mt][1], s2 = sc[mt][2], s3 = sc[mt][3];
      float mx4 = fmaxf(fmaxf(s0, s1), fmaxf(s2, s3));
      float nm = fmaxf(Mx[mt], mx4);
      Zs[mt] = Zs[mt] * __expf(Mx[mt] - nm) + __expf(s0 - nm) + __expf(s1 - nm) +
               __expf(s2 - nm) + __expf(s3 - nm);
      Mx[mt] = nm;
    }
  }
  // combine the 4 hi-groups (lanes sharing lo)
#pragma unroll
  for (int off = 16; off <= 32; off <<= 1)
#pragma unroll
    for (int mt = 0; mt < 4; mt++) {
      float oM = __shfl_xor(Mx[mt], off, 64);
      float oZ = __shfl_xor(Zs[mt], off, 64);
      float nm = fmaxf(Mx[mt], oM);
      Zs[mt] = Zs[mt] * __expf(Mx[mt] - nm) + oZ * __expf(oM - nm);
      Mx[mt] = nm;
    }
  if (hi == 0)
#pragma unroll
    for (int mt = 0; mt < 4; mt++) {
      redM[wave][mt * 16 + lo] = Mx[mt];
      redZ[wave][mt * 16 + lo] = Zs[mt];
    }
  __syncthreads();
  if (t < 64) {
    float M = redM[0][t], Z = redZ[0][t];
#pragma unroll
    for (int w = 1; w < 8; w++) {
      float m2 = redM[w][t], z2 = redZ[w][t];
      float nm = fmaxf(M, m2);
      Z = Z * __expf(M - nm) + z2 * __expf(m2 - nm);
      M = nm;
    }
    statM[t] = M;
    statZ[t] = 0.5f / Z;
  }
  __syncthreads();

  float Mv[4], Zi2[4];
#pragma unroll
  for (int mt = 0; mt < 4; mt++) {
    Mv[mt] = statM[mt * 16 + lo];
    Zi2[mt] = statZ[mt * 16 + lo];
  }
  const int cbase = wave * 32;
  float S1v[2][4];
#pragma unroll
  for (int ct = 0; ct < 2; ct++)
#pragma unroll
    for (int r = 0; r < 4; r++) S1v[ct][r] = S1[cbase + ct * 16 + hi * 4 + r];

  f32x4 acc[2][4];
#pragma unroll
  for (int ct = 0; ct < 2; ct++)
#pragma unroll
    for (int mt = 0; mt < 4; mt++) acc[ct][mt] = (f32x4){0.f, 0.f, 0.f, 0.f};

  // ---- main loop: recompute scores -> d tile (LDS) -> PV MFMA ----
  for (int nt = 0; nt < 32; nt++) {
    const int nb = nt * 128;
    // phase A: S^T tiles for this wave's 16-n stripe
    const int nr = nb + wave * 16 + lo;
    bf16x8 fb0 = *(const bf16x8*)&FB[nr * 64 + hi * 8];
    bf16x8 fb1 = *(const bf16x8*)&FB[nr * 64 + 32 + hi * 8];
    f32x4 sc[4];
#pragma unroll
    for (int mt = 0; mt < 4; mt++) {
      f32x4 z = {0.f, 0.f, 0.f, 0.f};
      z = __builtin_amdgcn_mfma_f32_16x16x32_bf16(fb0, faf[mt][0], z, 0, 0, 0);
      sc[mt] = __builtin_amdgcn_mfma_f32_16x16x32_bf16(fb1, faf[mt][1], z, 0, 0, 0);
    }
    __syncthreads();   // previous phase B finished reading d_lds
#pragma unroll
    for (int mt = 0; mt < 4; mt++) {
      union { u16 h[4]; uint2 v; } pk;
#pragma unroll
      for (int r = 0; r < 4; r++) {
        float xe = __expf(sc[mt][r] - Mv[mt]) * Zi2[mt];      // x = p/2 in [0, 0.5]
        float x2 = xe * xe;
        float i5 = fmaf(x2, -6.6666667e-2f, 1.6666667e-1f);   // 1/6 - x2/15
        float j5 = fmaf(x2, i5, -0.5f);                       // -0.5 + x2*(...)
        pk.h[r] = f2b(xe * j5);                               // d = -0.5*tanh(x)
      }
      int m = mt * 16 + lo;
      int nloc = wave * 16 + hi * 4;
      *(uint2*)&d_lds[m * 128 + (nloc ^ ((m & 7) * 8))] = pk.v;
    }
    __syncthreads();
    // phase B: acc[c][m] += f1[c, nb+k] * d[m, k]  (K = 128 as 4 MFMA steps)
#pragma unroll
    for (int ks = 0; ks < 4; ks++) {
      bf16x8 bfrag[4];
#pragma unroll
      for (int mt = 0; mt < 4; mt++) {
        int m = mt * 16 + lo;
        bfrag[mt] = *(const bf16x8*)&d_lds[m * 128 + ((ks * 32 + hi * 8) ^ ((m & 7) * 8))];
      }
#pragma unroll
      for (int ct = 0; ct < 2; ct++) {
        bf16x8 afrag = *(const bf16x8*)&F1[(cbase + ct * 16 + lo) * Nn + nb + ks * 32 + hi * 8];
#pragma unroll
        for (int mt = 0; mt < 4; mt++)
          acc[ct][mt] = __builtin_amdgcn_mfma_f32_16x16x32_bf16(afrag, bfrag[mt], acc[ct][mt], 0, 0, 0);
      }
    }
  }

  // ---- epilogue: out = alpha*(0.5*S1 + acc) + x ----
  const float alpha = alphaPtr[0];
#pragma unroll
  for (int ct = 0; ct < 2; ct++)
#pragma unroll
    for (int mt = 0; mt < 4; mt++)
#pragma unroll
      for (int r = 0; r < 4; r++) {
        int c = cbase + ct * 16 + hi * 4 + r;
        int m = m0 + mt * 16 + lo;
        int idx = (b * Cn + c) * Nn + m;
        out[idx] = fmaf(alpha, acc[ct][mt][r] + 0.5f * S1v[ct][r], x[idx]);
      }
}

// ---------------------------------------------------------------------------
extern "C" void kernel_launch(void* const* d_in, const int* in_sizes, int n_in,
                              void* d_out, int out_size, void* d_ws, size_t ws_size,
                              hipStream_t stream) {
  (void)in_sizes; (void)n_in; (void)out_size; (void)ws_size;
  const float* x1    = (const float*)d_in[0];
  const float* x2    = (const float*)d_in[1];
  const float* x     = (const float*)d_in[2];
  const float* gamma = (const float*)d_in[3];
  const float* beta  = (const float*)d_in[4];
  const float* mean  = (const float*)d_in[5];
  const float* var   = (const float*)d_in[6];
  const float* Wb    = (const float*)d_in[7];
  const float* bb    = (const float*)d_in[8];
  const float* Wc    = (const float*)d_in[9];
  const float* bc    = (const float*)d_in[10];
  const float* Wd    = (const float*)d_in[11];
  const float* bd    = (const float*)d_in[12];
  const float* alpha = (const float*)d_in[13];
  float* out = (float*)d_out;
  float* ws  = (float*)d_ws;

  k_fold<<<dim3(CKn, 2), 256, 0, stream>>>(Wb, bb, Wc, bc, gamma, beta, mean, var, ws);
  k_feat_ab<<<dim3(Nn / 128, 2, Bn), 256, 0, stream>>>(x1, x2, ws);
  k_feat_d<<<dim3(Nn / 128, Cn / 64, Bn), 256, 0, stream>>>(x, Wd, bd, ws);
  k_fused<<<dim3(Nn / 64, Bn), 512, 0, stream>>>(x, alpha, ws, out);
}

// Round 5
// 244.091 us; speedup vs baseline: 4.4718x; 1.2894x over previous
//
#include <hip/hip_runtime.h>
#include <math.h>

#define Bn 4
#define Cn 256
#define CKn 64
#define Nn 4096
#define EPSf 1e-5f

// ---- fp32 ws region (float offsets) ----
#define OFF_BEFFB 0        // 64
#define OFF_BEFFC 64       // 64
#define OFF_SX    128      // Bn*Cn fp32 column sums of x
#define OFF_S1    1152     // Bn*Cn fp32 exact f1 row sums
#define OFF_U16   2176     // u16 region starts (byte 8704, 16B aligned)
// ---- u16 region offsets ----
#define U_WEFFB 0          // [64][256] bf16
#define U_WEFFC 16384      // [64][256] bf16
#define U_WD    32768      // [256][256] bf16
#define U_FA    98304      // [b][n][64]  : b*262144 + n*64 + k
#define U_FB    1146880    // [b][n][64]
#define U_F1    2195456    // [b][c][n]   : b*1048576 + c*4096 + n

typedef unsigned short u16;
using bf16x8 = __attribute__((ext_vector_type(8))) __bf16;
using f32x4  = __attribute__((ext_vector_type(4))) float;

__device__ __forceinline__ u16 f2b(float x) {
  __bf16 h = (__bf16)x;
  return __builtin_bit_cast(unsigned short, h);
}

// ---------------------------------------------------------------------------
// Fold BN into conv weights (bf16) + beff fp32; also cvt Wd -> bf16.
// grid (64, 3), block 256. y=0: Wb->WeffB, y=1: Wc->WeffC, y=2: Wd cvt.
// ---------------------------------------------------------------------------
__global__ __launch_bounds__(256)
void k_fold(const float* __restrict__ Wb, const float* __restrict__ bb,
            const float* __restrict__ Wc, const float* __restrict__ bc,
            const float* __restrict__ gamma, const float* __restrict__ beta,
            const float* __restrict__ mean, const float* __restrict__ var,
            const float* __restrict__ Wd, float* __restrict__ ws) {
  const int k = blockIdx.x, which = blockIdx.y, c = threadIdx.x;
  u16* U = (u16*)(ws + OFF_U16);
  if (which == 2) {
#pragma unroll
    for (int r = 0; r < 4; r++) {
      int row = k * 4 + r;
      U[U_WD + row * 256 + c] = f2b(Wd[row * 256 + c]);
    }
    return;
  }
  const float* W = which ? Wc : Wb;
  const float* bias = which ? bc : bb;
  u16* Weff = U + (which ? U_WEFFC : U_WEFFB);
  float* beff = ws + (which ? OFF_BEFFC : OFF_BEFFB);
  float s = gamma[c] * rsqrtf(var[c] + EPSf);
  float tt = beta[c] - mean[c] * s;
  float w = W[k * Cn + c];
  Weff[k * Cn + c] = f2b(w * s);
  __shared__ float red[256];
  red[c] = w * tt;
  __syncthreads();
  for (int off = 128; off > 0; off >>= 1) {
    if (c < off) red[c] += red[c + off];
    __syncthreads();
  }
  if (c == 0) beff[k] = bias[k] + red[0];
}

// ---------------------------------------------------------------------------
// Sx[b][k] = sum_n x[b,k,n] (fp32). grid (Cn, Bn), block 256.
// ---------------------------------------------------------------------------
__global__ __launch_bounds__(256)
void k_sx(const float* __restrict__ x, float* __restrict__ ws) {
  const int k = blockIdx.x, b = blockIdx.y, t = threadIdx.x;
  const float* row = x + (b * Cn + k) * Nn;
  float s = 0.f;
#pragma unroll
  for (int i = 0; i < 4; i++) {
    float4 v = *(const float4*)&row[i * 1024 + t * 4];
    s += v.x + v.y + v.z + v.w;
  }
#pragma unroll
  for (int off = 1; off < 64; off <<= 1) s += __shfl_xor(s, off, 64);
  __shared__ float p[4];
  if ((t & 63) == 0) p[t >> 6] = s;
  __syncthreads();
  if (t == 0) ws[OFF_SX + b * Cn + k] = p[0] + p[1] + p[2] + p[3];
}

// ---------------------------------------------------------------------------
// S1[b][c] = Wd[c,:].Sx[b,:] + 4096*bd[c]  (exact fp32 common mode).
// grid (Bn), block 256.
// ---------------------------------------------------------------------------
__global__ __launch_bounds__(256)
void k_s1(const float* __restrict__ Wd, const float* __restrict__ bd,
          float* __restrict__ ws) {
  const int b = blockIdx.x, c = threadIdx.x;
  __shared__ float sx[256];
  sx[c] = ws[OFF_SX + b * Cn + c];
  __syncthreads();
  float acc = 4096.f * bd[c];
  for (int k = 0; k < 256; k++) acc = fmaf(Wd[c * 256 + k], sx[k], acc);
  ws[OFF_S1 + b * Cn + c] = acc;
}

// ---------------------------------------------------------------------------
// fa/fb via MFMA: FA[n][k] = sum_c x(c,n)*Weff(k,c) + beff(k), bf16 out.
// A-operand: x^T rows n (per-lane strided global loads, line-coalesced);
// B-operand: Weff bf16 rows k_out (contiguous 16B).
// grid (Nn/64, 2, Bn), block 256 (4 waves, each one 16-n tile x 64 k_out).
// ---------------------------------------------------------------------------
__global__ __launch_bounds__(256)
void k_feat_ab(const float* __restrict__ x1, const float* __restrict__ x2,
               float* __restrict__ ws) {
  const int blk = blockIdx.x, which = blockIdx.y, b = blockIdx.z;
  u16* U = (u16*)(ws + OFF_U16);
  const u16* WB = U + (which ? U_WEFFC : U_WEFFB);
  const float* beff = ws + (which ? OFF_BEFFC : OFF_BEFFB);
  const float* X = (which ? x2 : x1) + b * Cn * Nn;
  u16* Y = U + (which ? U_FB : U_FA) + b * 262144;
  const int t = threadIdx.x, wave = t >> 6, lo = t & 15, hi = (t & 63) >> 4;
  const int n0 = blk * 64 + wave * 16;

  f32x4 acc[4];
#pragma unroll
  for (int kt = 0; kt < 4; kt++) acc[kt] = (f32x4){0.f, 0.f, 0.f, 0.f};

  for (int c0 = 0; c0 < 256; c0 += 32) {
    bf16x8 af;
#pragma unroll
    for (int j = 0; j < 8; j++) af[j] = (__bf16)X[(c0 + hi * 8 + j) * Nn + n0 + lo];
#pragma unroll
    for (int kt = 0; kt < 4; kt++) {
      bf16x8 bfr = *(const bf16x8*)&WB[(kt * 16 + lo) * 256 + c0 + hi * 8];
      acc[kt] = __builtin_amdgcn_mfma_f32_16x16x32_bf16(af, bfr, acc[kt], 0, 0, 0);
    }
  }
#pragma unroll
  for (int kt = 0; kt < 4; kt++) {
    float bv = beff[kt * 16 + lo];
#pragma unroll
    for (int r = 0; r < 4; r++)
      Y[(n0 + hi * 4 + r) * 64 + kt * 16 + lo] = f2b(acc[kt][r] + bv);
  }
}

// ---------------------------------------------------------------------------
// f1 via MFMA: F1[c][n] = sum_k Wd(c,k)*x(k,n) + bd(c), bf16 out.
// A: Wd bf16 rows c (contiguous); B: x cols n (strided global, line-coalesced).
// grid (Nn/32, Bn), block 512 (8 waves; wave w: c in [32w,32w+32), 2 n-tiles).
// ---------------------------------------------------------------------------
__global__ __launch_bounds__(512)
void k_feat_d(const float* __restrict__ x, const float* __restrict__ bd,
              float* __restrict__ ws) {
  const int blk = blockIdx.x, b = blockIdx.y;
  u16* U = (u16*)(ws + OFF_U16);
  const u16* WD = U + U_WD;
  const float* X = x + b * Cn * Nn;
  u16* F1 = U + U_F1 + b * 1048576;
  const int t = threadIdx.x, wave = t >> 6, lo = t & 15, hi = (t & 63) >> 4;
  const int n0 = blk * 32;
  const int c0 = wave * 32;

  f32x4 acc[2][2];
#pragma unroll
  for (int ci = 0; ci < 2; ci++)
#pragma unroll
    for (int nt = 0; nt < 2; nt++) acc[ci][nt] = (f32x4){0.f, 0.f, 0.f, 0.f};

  for (int k0 = 0; k0 < 256; k0 += 32) {
    bf16x8 bfr[2];
#pragma unroll
    for (int nt = 0; nt < 2; nt++)
#pragma unroll
      for (int j = 0; j < 8; j++)
        bfr[nt][j] = (__bf16)X[(k0 + hi * 8 + j) * Nn + n0 + nt * 16 + lo];
#pragma unroll
    for (int ci = 0; ci < 2; ci++) {
      bf16x8 afr = *(const bf16x8*)&WD[(c0 + ci * 16 + lo) * 256 + k0 + hi * 8];
#pragma unroll
      for (int nt = 0; nt < 2; nt++)
        acc[ci][nt] = __builtin_amdgcn_mfma_f32_16x16x32_bf16(afr, bfr[nt], acc[ci][nt], 0, 0, 0);
    }
  }
#pragma unroll
  for (int ci = 0; ci < 2; ci++)
#pragma unroll
    for (int r = 0; r < 4; r++) {
      int c = c0 + ci * 16 + hi * 4 + r;
      float bv = bd[c];
#pragma unroll
      for (int nt = 0; nt < 2; nt++)
        F1[c * Nn + n0 + nt * 16 + lo] = f2b(acc[ci][nt][r] + bv);
    }
}

// ---------------------------------------------------------------------------
// Fused stats + attention + PV (MFMA). grid (Nn/64, Bn), block 512.
// Double-buffered d_lds -> 1 barrier/iter; F1 fragments prefetched pre-barrier;
// setprio(1) around PV MFMA cluster.
// d = att - 0.5 = -0.5*tanh(p/2); out = alpha*(0.5*S1 + sum f1*d) + x
// ---------------------------------------------------------------------------
__global__ __launch_bounds__(512)
void k_fused(const float* __restrict__ x, const float* __restrict__ alphaPtr,
             const float* __restrict__ wsf, float* __restrict__ out) {
  const int m0 = blockIdx.x * 64;
  const int b = blockIdx.y;
  const u16* U = (const u16*)(wsf + OFF_U16);
  const u16* FA = U + U_FA + b * 262144;
  const u16* FB = U + U_FB + b * 262144;
  const u16* F1 = U + U_F1 + b * 1048576;
  const float* S1 = wsf + OFF_S1 + b * Cn;

  const int t = threadIdx.x;
  const int wave = t >> 6, lane = t & 63, lo = lane & 15, hi = lane >> 4;

  __shared__ u16 d_lds[2][64 * 128];         // swizzled [m][n ^ ((m&7)*8)]
  __shared__ float redM[8][64], redZ[8][64];
  __shared__ float statM[64], statZ[64];     // M*, 0.5/Z*

  bf16x8 faf[4][2];
#pragma unroll
  for (int mt = 0; mt < 4; mt++)
#pragma unroll
    for (int ks = 0; ks < 2; ks++)
      faf[mt][ks] = *(const bf16x8*)&FA[(m0 + mt * 16 + lo) * 64 + ks * 32 + hi * 8];

  // ---- stats pass ----
  float Mx[4], Zs[4];
#pragma unroll
  for (int mt = 0; mt < 4; mt++) { Mx[mt] = -1e30f; Zs[mt] = 0.f; }

  for (int it = 0; it < 32; it++) {
    const int nr = it * 128 + wave * 16 + lo;
    bf16x8 fb0 = *(const bf16x8*)&FB[nr * 64 + hi * 8];
    bf16x8 fb1 = *(const bf16x8*)&FB[nr * 64 + 32 + hi * 8];
    f32x4 sc[4];
#pragma unroll
    for (int mt = 0; mt < 4; mt++) {
      f32x4 z = {0.f, 0.f, 0.f, 0.f};
      z = __builtin_amdgcn_mfma_f32_16x16x32_bf16(fb0, faf[mt][0], z, 0, 0, 0);
      sc[mt] = __builtin_amdgcn_mfma_f32_16x16x32_bf16(fb1, faf[mt][1], z, 0, 0, 0);
    }
#pragma unroll
    for (int mt = 0; mt < 4; mt++) {
      float s0 = sc[mt][0], s1 = sc[mt][1], s2 = sc[mt][2], s3 = sc[mt][3];
      float mx4 = fmaxf(fmaxf(s0, s1), fmaxf(s2, s3));
      float nm = fmaxf(Mx[mt], mx4);
      Zs[mt] = Zs[mt] * __expf(Mx[mt] - nm) + __expf(s0 - nm) + __expf(s1 - nm) +
               __expf(s2 - nm) + __expf(s3 - nm);
      Mx[mt] = nm;
    }
  }
#pragma unroll
  for (int off = 16; off <= 32; off <<= 1)
#pragma unroll
    for (int mt = 0; mt < 4; mt++) {
      float oM = __shfl_xor(Mx[mt], off, 64);
      float oZ = __shfl_xor(Zs[mt], off, 64);
      float nm = fmaxf(Mx[mt], oM);
      Zs[mt] = Zs[mt] * __expf(Mx[mt] - nm) + oZ * __expf(oM - nm);
      Mx[mt] = nm;
    }
  if (hi == 0)
#pragma unroll
    for (int mt = 0; mt < 4; mt++) {
      redM[wave][mt * 16 + lo] = Mx[mt];
      redZ[wave][mt * 16 + lo] = Zs[mt];
    }
  __syncthreads();
  if (t < 64) {
    float M = redM[0][t], Z = redZ[0][t];
#pragma unroll
    for (int w = 1; w < 8; w++) {
      float m2 = redM[w][t], z2 = redZ[w][t];
      float nm = fmaxf(M, m2);
      Z = Z * __expf(M - nm) + z2 * __expf(m2 - nm);
      M = nm;
    }
    statM[t] = M;
    statZ[t] = 0.5f / Z;
  }
  __syncthreads();

  float Mv[4], Zi2[4];
#pragma unroll
  for (int mt = 0; mt < 4; mt++) {
    Mv[mt] = statM[mt * 16 + lo];
    Zi2[mt] = statZ[mt * 16 + lo];
  }
  const int cbase = wave * 32;
  float S1v[2][4];
#pragma unroll
  for (int ct = 0; ct < 2; ct++)
#pragma unroll
    for (int r = 0; r < 4; r++) S1v[ct][r] = S1[cbase + ct * 16 + hi * 4 + r];

  f32x4 acc[2][4];
#pragma unroll
  for (int ct = 0; ct < 2; ct++)
#pragma unroll
    for (int mt = 0; mt < 4; mt++) acc[ct][mt] = (f32x4){0.f, 0.f, 0.f, 0.f};

  // ---- main loop ----
  for (int nt = 0; nt < 32; nt++) {
    const int nb = nt * 128;
    const int nr = nb + wave * 16 + lo;
    bf16x8 fb0 = *(const bf16x8*)&FB[nr * 64 + hi * 8];
    bf16x8 fb1 = *(const bf16x8*)&FB[nr * 64 + 32 + hi * 8];
    f32x4 sc[4];
#pragma unroll
    for (int mt = 0; mt < 4; mt++) {
      f32x4 z = {0.f, 0.f, 0.f, 0.f};
      z = __builtin_amdgcn_mfma_f32_16x16x32_bf16(fb0, faf[mt][0], z, 0, 0, 0);
      sc[mt] = __builtin_amdgcn_mfma_f32_16x16x32_bf16(fb1, faf[mt][1], z, 0, 0, 0);
    }
    // prefetch F1 fragments for this iter (independent -> overlaps below)
    bf16x8 afr[2][4];
#pragma unroll
    for (int ct = 0; ct < 2; ct++)
#pragma unroll
      for (int ks = 0; ks < 4; ks++)
        afr[ct][ks] = *(const bf16x8*)&F1[(cbase + ct * 16 + lo) * Nn + nb + ks * 32 + hi * 8];
    // d tile -> LDS (double-buffered)
    u16* db = &d_lds[nt & 1][0];
#pragma unroll
    for (int mt = 0; mt < 4; mt++) {
      union { u16 h[4]; uint2 v; } pk;
#pragma unroll
      for (int r = 0; r < 4; r++) {
        float xe = __expf(sc[mt][r] - Mv[mt]) * Zi2[mt];      // x = p/2 in [0,0.5]
        float x2 = xe * xe;
        float i5 = fmaf(x2, -6.6666667e-2f, 1.6666667e-1f);
        float j5 = fmaf(x2, i5, -0.5f);
        pk.h[r] = f2b(xe * j5);                               // d = -0.5*tanh(x)
      }
      int m = mt * 16 + lo;
      int nloc = wave * 16 + hi * 4;
      *(uint2*)&db[m * 128 + (nloc ^ ((m & 7) * 8))] = pk.v;
    }
    __syncthreads();
    // PV
    __builtin_amdgcn_s_setprio(1);
#pragma unroll
    for (int ks = 0; ks < 4; ks++) {
      bf16x8 bfrag[4];
#pragma unroll
      for (int mt = 0; mt < 4; mt++) {
        int m = mt * 16 + lo;
        bfrag[mt] = *(const bf16x8*)&db[m * 128 + ((ks * 32 + hi * 8) ^ ((m & 7) * 8))];
      }
#pragma unroll
      for (int ct = 0; ct < 2; ct++)
#pragma unroll
        for (int mt = 0; mt < 4; mt++)
          acc[ct][mt] = __builtin_amdgcn_mfma_f32_16x16x32_bf16(afr[ct][ks], bfrag[mt], acc[ct][mt], 0, 0, 0);
    }
    __builtin_amdgcn_s_setprio(0);
  }

  // ---- epilogue ----
  const float alpha = alphaPtr[0];
#pragma unroll
  for (int ct = 0; ct < 2; ct++)
#pragma unroll
    for (int mt = 0; mt < 4; mt++)
#pragma unroll
      for (int r = 0; r < 4; r++) {
        int c = cbase + ct * 16 + hi * 4 + r;
        int m = m0 + mt * 16 + lo;
        int idx = (b * Cn + c) * Nn + m;
        out[idx] = fmaf(alpha, acc[ct][mt][r] + 0.5f * S1v[ct][r], x[idx]);
      }
}

// ---------------------------------------------------------------------------
extern "C" void kernel_launch(void* const* d_in, const int* in_sizes, int n_in,
                              void* d_out, int out_size, void* d_ws, size_t ws_size,
                              hipStream_t stream) {
  (void)in_sizes; (void)n_in; (void)out_size; (void)ws_size;
  const float* x1    = (const float*)d_in[0];
  const float* x2    = (const float*)d_in[1];
  const float* x     = (const float*)d_in[2];
  const float* gamma = (const float*)d_in[3];
  const float* beta  = (const float*)d_in[4];
  const float* mean  = (const float*)d_in[5];
  const float* var   = (const float*)d_in[6];
  const float* Wb    = (const float*)d_in[7];
  const float* bb    = (const float*)d_in[8];
  const float* Wc    = (const float*)d_in[9];
  const float* bc    = (const float*)d_in[10];
  const float* Wd    = (const float*)d_in[11];
  const float* bd    = (const float*)d_in[12];
  const float* alpha = (const float*)d_in[13];
  float* out = (float*)d_out;
  float* ws  = (float*)d_ws;

  k_fold<<<dim3(CKn, 3), 256, 0, stream>>>(Wb, bb, Wc, bc, gamma, beta, mean, var, Wd, ws);
  k_sx<<<dim3(Cn, Bn), 256, 0, stream>>>(x, ws);
  k_s1<<<dim3(Bn), 256, 0, stream>>>(Wd, bd, ws);
  k_feat_ab<<<dim3(Nn / 64, 2, Bn), 256, 0, stream>>>(x1, x2, ws);
  k_feat_d<<<dim3(Nn / 32, Bn), 512, 0, stream>>>(x, bd, ws);
  k_fused<<<dim3(Nn / 64, Bn), 512, 0, stream>>>(x, alpha, ws, out);
}